// Round 9
// baseline (169.096 us; speedup 1.0000x reference)
//
#include <hip/hip_runtime.h>
#include <hip/hip_bf16.h>

#define N 4096
#define IND 256
#define OUTD 128
#define NEGV -9000000000000000.0f

// ---------------- Kernel A: wh = lstm_out @ W  (4096x256 @ 256x128) ----------------
__global__ __launch_bounds__(256) void wh_kernel(const float* __restrict__ x,
                                                 const float* __restrict__ W,
                                                 float* __restrict__ wh) {
    __shared__ float xs[8][IND];
    const int t = threadIdx.x;
    const int i0 = blockIdx.x * 8;
    const float4* src = (const float4*)(x + (size_t)i0 * IND);
    float4* dst = (float4*)&xs[0][0];
    dst[t] = src[t];
    dst[t + 256] = src[t + 256];
    __syncthreads();
    const int c = t & 127;
    const int rbase = (t >> 7) * 4;
    float acc[4] = {0.f, 0.f, 0.f, 0.f};
    #pragma unroll 4
    for (int k = 0; k < IND; k += 4) {
        const float w0 = W[(k + 0) * OUTD + c];
        const float w1 = W[(k + 1) * OUTD + c];
        const float w2 = W[(k + 2) * OUTD + c];
        const float w3 = W[(k + 3) * OUTD + c];
        #pragma unroll
        for (int r = 0; r < 4; ++r) {
            const float4 xv = *(const float4*)&xs[rbase + r][k];
            acc[r] = fmaf(xv.x, w0, acc[r]);
            acc[r] = fmaf(xv.y, w1, acc[r]);
            acc[r] = fmaf(xv.z, w2, acc[r]);
            acc[r] = fmaf(xv.w, w3, acc[r]);
        }
    }
    #pragma unroll
    for (int r = 0; r < 4; ++r)
        wh[(size_t)(i0 + rbase + r) * OUTD + c] = acc[r];
}

// ---------------- Kernel A2: s_i = wh @ a_i, s_j = wh @ a_j ----------------
__global__ __launch_bounds__(128) void sij_kernel(const float* __restrict__ wh,
                                                  const float* __restrict__ a,
                                                  float* __restrict__ s_i,
                                                  float* __restrict__ s_j) {
    const int i = blockIdx.x;
    const int c = threadIdx.x;
    float v = wh[(size_t)i * OUTD + c];
    float p = v * a[c];              // a_i = a[0:128]
    float q = v * a[OUTD + 5 + c];   // a_j = a[133:261]
    #pragma unroll
    for (int off = 32; off >= 1; off >>= 1) {
        p += __shfl_down(p, off);
        q += __shfl_down(q, off);
    }
    __shared__ float tmp[4];
    if ((c & 63) == 0) { tmp[c >> 6] = p; tmp[2 + (c >> 6)] = q; }
    __syncthreads();
    if (c == 0) { s_i[i] = tmp[0] + tmp[1]; s_j[i] = tmp[2] + tmp[3]; }
}

// ---------------- Kernel B: flash GAT over a j-chunk (async LDS edge staging) ----------------
// Grid = 512 i-groups x NCH=2 chunks = 1024 blocks x 256 threads -> 4 blocks/CU
// (round-8 had 2/CU; HBM duty was the 2x gap). Each block: 8 rows x 2048 j as
// 32 subtiles of BJ=64, online softmax, raw partial (part, m, l) out; tiny merge.
// Per subtile (structure proven in round 8):
//   [1] async global_load_lds stage of st+1 -> E[b^1] (zero VGPR, in flight)
//   [2] scores(st) from E[b] -> P[b] (wave w owns rows 2w, 2w+1)
//   [3] lgkmcnt(0)-only barrier (P visible; stage NOT drained)
//   [4] PV(st): 8 cols x 8 rows/thread from P[b] + wh (L2-resident, 1 GB total)
//   [5] __syncthreads (drains vmcnt -> E[b^1] ready)
// VGPR-cap model (fitted r3/5/6/7, confirmed r8): cap = 512/(2*arg2);
// __launch_bounds__(256,1) -> 256. Spill sentinel: WRITE_SIZE (~8 MB legit).
#define BI 8
#define BJ 64
#define NCH 2
#define CHJ (N / NCH)          // 2048
#define NSUB (CHJ / BJ)        // 32
#define PSTR 68                // P row stride (16B-aligned: 68*4=272=17*16)
#define RSTR 132               // red row stride (epilogue overlay on E)
#define EF4 (BI * BJ * 5 / 4)  // 640 float4 per buffer (10 KB)

#define FMA4(A, pv, wv)                  \
    A.x = fmaf(pv, wv.x, A.x);           \
    A.y = fmaf(pv, wv.y, A.y);           \
    A.z = fmaf(pv, wv.z, A.z);           \
    A.w = fmaf(pv, wv.w, A.w);

__device__ __forceinline__ void gload_lds16(const void* g, void* l) {
    __builtin_amdgcn_global_load_lds(
        (const __attribute__((address_space(1))) unsigned int*)(g),
        (__attribute__((address_space(3))) unsigned int*)(l),
        16, 0, 0);
}

__global__ __launch_bounds__(256, 1) void gat_chunk(const float* __restrict__ edges,
                                                    const float* __restrict__ wh,
                                                    const float* __restrict__ s_iv,
                                                    const float* __restrict__ s_jv,
                                                    const float* __restrict__ a,
                                                    float* __restrict__ part,
                                                    float* __restrict__ mout,
                                                    float* __restrict__ lout) {
    __shared__ float E[2][EF4 * 4];      // 20 KB (epilogue: red overlay spans both)
    __shared__ float P[2][BI][PSTR];     // 4.4 KB
    __shared__ float fbuf[2][BI];

    const int t = threadIdx.x;
    const int ib = blockIdx.x & 511;
    const int ch = blockIdx.x >> 9;
    const int i0 = ib * BI;
    const int jbase = ch * CHJ;

    const int w = t >> 6;
    const int s = t & 63;
    const int r0 = 2 * w, r1 = r0 + 1;

    const float ae0 = a[OUTD + 0], ae1 = a[OUTD + 1], ae2 = a[OUTD + 2],
                ae3 = a[OUTD + 3], ae4 = a[OUTD + 4];
    const float si0 = s_iv[i0 + r0];
    const float si1 = s_iv[i0 + r1];

    const int cg = t & 15;   // col group -> cols c8..c8+7
    const int c8 = cg * 8;
    const int js = t >> 4;   // j slice 0..15 (4 j each)

    // Stage sources: float4 f of the 640-float4 tile; row = f/80, rem = f%80
    // are subtile-invariant. k=0: f=t, k=1: f=256+t, k=2: f=512+t (t<128 only).
    const char* g0; const char* g1; const char* g2;
    {
        const char* eb = (const char*)edges + (size_t)jbase * 20;
        #define MKG(F, VAR)                                                    \
        {   const int f = (F);                                                 \
            const int row = f / 80;                                            \
            const int rem = f - row * 80;                                      \
            VAR = eb + (size_t)(i0 + row) * (N * 20) + (size_t)rem * 16; }
        MKG(t, g0) MKG(256 + t, g1) MKG(512 + (t & 127), g2)
        #undef MKG
    }
    #define STAGE(BB, ST)                                                      \
    {   const size_t jo = (size_t)(ST) * (BJ * 20);                            \
        gload_lds16(g0 + jo, &E[BB][t * 4]);                                   \
        gload_lds16(g1 + jo, &E[BB][(256 + t) * 4]);                           \
        if (t < 128) gload_lds16(g2 + jo, &E[BB][(512 + t) * 4]); }

    float m0 = -1e30f, m1 = -1e30f, l0 = 0.f, l1 = 0.f;
    float4 acc[BI][2];
    #pragma unroll
    for (int rr = 0; rr < BI; ++rr) {
        acc[rr][0] = make_float4(0.f, 0.f, 0.f, 0.f);
        acc[rr][1] = make_float4(0.f, 0.f, 0.f, 0.f);
    }

    // prologue
    STAGE(0, 0)
    float sj = s_jv[jbase + s];
    __syncthreads();   // E[0] ready

    for (int st = 0; st < NSUB; ++st) {
        const int b = st & 1;
        const int jb = st * BJ;
        const bool pf = (st + 1 < NSUB);

        // ---- [1] async stage of subtile st+1 ----
        float sj_nx = 0.f;
        if (pf) {
            STAGE(b ^ 1, st + 1)
            sj_nx = s_jv[jbase + jb + BJ + s];
        }

        // ---- [2] scores(st) from E[b] ----
        {
            const float* Eb = &E[b][0];
            const int e0 = (r0 * BJ + s) * 5;
            const int e1 = (r1 * BJ + s) * 5;
            float sc0, sc1;
            {
                float d = Eb[e0 + 4] * ae4;
                d = fmaf(Eb[e0 + 0], ae0, d);
                d = fmaf(Eb[e0 + 1], ae1, d);
                d = fmaf(Eb[e0 + 2], ae2, d);
                d = fmaf(Eb[e0 + 3], ae3, d);
                float v = si0 + d + sj;
                v = fmaxf(v, 0.2f * v);                    // leaky relu before mask
                if (jbase + jb + s == i0 + r0) v = NEGV;   // diagonal
                sc0 = v;
            }
            {
                float d = Eb[e1 + 4] * ae4;
                d = fmaf(Eb[e1 + 0], ae0, d);
                d = fmaf(Eb[e1 + 1], ae1, d);
                d = fmaf(Eb[e1 + 2], ae2, d);
                d = fmaf(Eb[e1 + 3], ae3, d);
                float v = si1 + d + sj;
                v = fmaxf(v, 0.2f * v);
                if (jbase + jb + s == i0 + r1) v = NEGV;
                sc1 = v;
            }
            float mx0 = sc0, mx1 = sc1;
            #pragma unroll
            for (int off = 32; off >= 1; off >>= 1) {
                mx0 = fmaxf(mx0, __shfl_xor(mx0, off));
                mx1 = fmaxf(mx1, __shfl_xor(mx1, off));
            }
            const float nm0 = fmaxf(m0, mx0);
            const float nm1 = fmaxf(m1, mx1);
            const float f0 = __expf(m0 - nm0);
            const float f1 = __expf(m1 - nm1);
            m0 = nm0; m1 = nm1;
            const float p0 = __expf(sc0 - m0);
            const float p1 = __expf(sc1 - m1);
            P[b][r0][s] = p0;
            P[b][r1][s] = p1;
            float ls0 = p0, ls1 = p1;
            #pragma unroll
            for (int off = 32; off >= 1; off >>= 1) {
                ls0 += __shfl_xor(ls0, off);
                ls1 += __shfl_xor(ls1, off);
            }
            l0 = l0 * f0 + ls0;
            l1 = l1 * f1 + ls1;
            if (s == 0) { fbuf[b][r0] = f0; fbuf[b][r1] = f1; }
        }

        // ---- [3] LDS-only barrier ----
        asm volatile("s_waitcnt lgkmcnt(0)" ::: "memory");
        __builtin_amdgcn_s_barrier();
        asm volatile("" ::: "memory");

        // ---- [4] PV(st): 8 cols x 8 rows per thread over 4 j ----
        #pragma unroll
        for (int rr = 0; rr < BI; ++rr) {
            const float f = fbuf[b][rr];
            acc[rr][0].x *= f; acc[rr][0].y *= f; acc[rr][0].z *= f; acc[rr][0].w *= f;
            acc[rr][1].x *= f; acc[rr][1].y *= f; acc[rr][1].z *= f; acc[rr][1].w *= f;
        }
        {
            const float* whp = wh + (size_t)(jbase + jb + js * 4) * OUTD + c8;
            float4 wa[4], wb[4];
            #pragma unroll
            for (int jj = 0; jj < 4; ++jj) {
                wa[jj] = *(const float4*)(whp + (size_t)jj * OUTD);
                wb[jj] = *(const float4*)(whp + (size_t)jj * OUTD + 4);
            }
            #pragma unroll
            for (int rr = 0; rr < BI; ++rr) {
                const float4 p = *(const float4*)&P[b][rr][js * 4];
                FMA4(acc[rr][0], p.x, wa[0]);
                FMA4(acc[rr][1], p.x, wb[0]);
                FMA4(acc[rr][0], p.y, wa[1]);
                FMA4(acc[rr][1], p.y, wb[1]);
                FMA4(acc[rr][0], p.z, wa[2]);
                FMA4(acc[rr][1], p.z, wb[2]);
                FMA4(acc[rr][0], p.w, wa[3]);
                FMA4(acc[rr][1], p.w, wb[3]);
            }
        }

        if (pf) sj = sj_nx;

        // ---- [5] full barrier: drains vmcnt -> E[b^1] staged ----
        __syncthreads();
    }

    // ---- epilogue: raw partial (no normalization here; merge does it) ----
    if (s == 0) {
        mout[ch * N + i0 + r0] = m0;
        mout[ch * N + i0 + r1] = m1;
        lout[ch * N + i0 + r0] = l0;
        lout[ch * N + i0 + r1] = l1;
    }
    #pragma unroll
    for (int rr = 0; rr < BI; ++rr) {
        #pragma unroll
        for (int h = 0; h < 2; ++h) {
            acc[rr][h].x += __shfl_xor(acc[rr][h].x, 16);
            acc[rr][h].y += __shfl_xor(acc[rr][h].y, 16);
            acc[rr][h].z += __shfl_xor(acc[rr][h].z, 16);
            acc[rr][h].w += __shfl_xor(acc[rr][h].w, 16);
            acc[rr][h].x += __shfl_xor(acc[rr][h].x, 32);
            acc[rr][h].y += __shfl_xor(acc[rr][h].y, 32);
            acc[rr][h].z += __shfl_xor(acc[rr][h].z, 32);
            acc[rr][h].w += __shfl_xor(acc[rr][h].w, 32);
        }
    }
    float* red = &E[0][0];   // 4*8*132 = 4224 floats <= 5120 available
    if (s < 16) {
        #pragma unroll
        for (int rr = 0; rr < BI; ++rr) {
            *(float4*)&red[(w * BI + rr) * RSTR + c8] = acc[rr][0];
            *(float4*)&red[(w * BI + rr) * RSTR + c8 + 4] = acc[rr][1];
        }
    }
    __syncthreads();
    {
        const int rr = t >> 5;
        const int c4 = (t & 31) * 4;
        const float4 v0 = *(const float4*)&red[(0 * BI + rr) * RSTR + c4];
        const float4 v1 = *(const float4*)&red[(1 * BI + rr) * RSTR + c4];
        const float4 v2 = *(const float4*)&red[(2 * BI + rr) * RSTR + c4];
        const float4 v3 = *(const float4*)&red[(3 * BI + rr) * RSTR + c4];
        float4 o;
        o.x = v0.x + v1.x + v2.x + v3.x;
        o.y = v0.y + v1.y + v2.y + v3.y;
        o.z = v0.z + v1.z + v2.z + v3.z;
        o.w = v0.w + v1.w + v2.w + v3.w;
        *(float4*)&part[((size_t)ch * N + (i0 + rr)) * OUTD + c4] = o;
    }
}

// ---------------- Kernel C: merge the 2 chunk partials ----------------
__global__ __launch_bounds__(256) void gat_merge(const float* __restrict__ part,
                                                 const float* __restrict__ mout,
                                                 const float* __restrict__ lout,
                                                 float* __restrict__ out) {
    const int idx = blockIdx.x * 256 + threadIdx.x;   // over N*OUTD
    const int i = idx >> 7;
    const float ma = mout[i];
    const float mb = mout[N + i];
    const float M = fmaxf(ma, mb);
    const float ea = __expf(ma - M);
    const float eb = __expf(mb - M);
    const float L = lout[i] * ea + lout[N + i] * eb;
    const float v = part[idx] * ea + part[(size_t)N * OUTD + idx] * eb;
    out[idx] = v / L;
}

extern "C" void kernel_launch(void* const* d_in, const int* in_sizes, int n_in,
                              void* d_out, int out_size, void* d_ws, size_t ws_size,
                              hipStream_t stream) {
    // inputs: 0=ids(int, unused), 1=lstm_out, 2=edges_list, 3=W, 4=a, 5=first(unused)
    const float* lstm_out = (const float*)d_in[1];
    const float* edges    = (const float*)d_in[2];
    const float* W        = (const float*)d_in[3];
    const float* a        = (const float*)d_in[4];
    float* out = (float*)d_out;

    float* wh   = (float*)d_ws;                  // 4096*128
    float* s_i  = wh + (size_t)N * OUTD;         // 4096
    float* s_j  = s_i + N;                       // 4096
    float* mout = s_j + N;                       // 2*4096
    float* lout = mout + (size_t)NCH * N;        // 2*4096
    float* part = lout + (size_t)NCH * N;        // 2*4096*128 (4 MB)

    wh_kernel<<<N / 8, 256, 0, stream>>>(lstm_out, W, wh);
    sij_kernel<<<N, 128, 0, stream>>>(wh, a, s_i, s_j);
    gat_chunk<<<512 * NCH, 256, 0, stream>>>(edges, wh, s_i, s_j, a, part, mout, lout);
    gat_merge<<<(N * OUTD) / 256, 256, 0, stream>>>(part, mout, lout, out);
}